// Round 9
// baseline (644.986 us; speedup 1.0000x reference)
//
#include <hip/hip_runtime.h>
#include <math.h>

#define HW 65536
#define NC 10
#define NT 12
#define LAMBDA_F 0.05f
#define PI_F 3.14159265358979323846f
// XOR-swizzle for wave-private LDS fft scratch
#define SWZ(i) ((i) ^ ((i) >> 4))
// part buffer rows (1024 floats each)
#define ROW_RS(it)  (it)            // rs_it partials: rows 0..9
#define ROW_PAR(it) (16 + 2*(it))   // Parseval pAp partials re/im: rows 16..35
#define NPART_ROWS 36

__device__ __forceinline__ float2 cadd(float2 a, float2 b){ return make_float2(a.x+b.x, a.y+b.y); }
__device__ __forceinline__ float2 csub(float2 a, float2 b){ return make_float2(a.x-b.x, a.y-b.y); }
__device__ __forceinline__ float2 cmul(float2 a, float2 b){ return make_float2(a.x*b.x-a.y*b.y, a.x*b.y+a.y*b.x); }
// conj(a)*b
__device__ __forceinline__ float2 cmulj(float2 a, float2 b){ return make_float2(a.x*b.x+a.y*b.y, a.x*b.y-a.y*b.x); }
__device__ __forceinline__ float2 cscale(float2 a, float s){ return make_float2(a.x*s, a.y*s); }

template<int SIGN>
__device__ __forceinline__ void radix4_nt(float2& a0, float2& a1, float2& a2, float2& a3){
  float2 t0=cadd(a0,a2), t1=csub(a0,a2), t2=cadd(a1,a3), t3=csub(a1,a3);
  float2 t3r;
  if constexpr (SIGN < 0) t3r = make_float2(t3.y, -t3.x); else t3r = make_float2(-t3.y, t3.x);
  a0=cadd(t0,t2); a1=cadd(t1,t3r); a2=csub(t0,t2); a3=csub(t1,t3r);
}

template<int SIGN>
__device__ __forceinline__ void radix4_tw(float2& a0, float2& a1, float2& a2, float2& a3, float2 w){
  if constexpr (SIGN > 0) w.y = -w.y;
  float2 w2 = cmul(w, w);
  float2 w3 = cmul(w, w2);
  a1 = cmul(a1, w); a2 = cmul(a2, w2); a3 = cmul(a3, w3);
  radix4_nt<SIGN>(a0, a1, a2, a3);
}

__device__ __forceinline__ float2 twf(int e){
  float s, c;
  __sincosf(-2.0f*PI_F*(float)e*(1.0f/256.0f), &s, &c);
  return make_float2(c, s);
}

// Single 256-pt Stockham radix-4 FFT, wave-private scratch b.
template<int SIGN>
__device__ __forceinline__ void fft256(float2* b, int j,
                                       float2 wA, float2 wB, float2 wC,
                                       float2& x0, float2& x1, float2& x2, float2& x3){
  radix4_nt<SIGN>(x0,x1,x2,x3);
  b[SWZ(4*j)]=x0; b[SWZ(4*j+1)]=x1; b[SWZ(4*j+2)]=x2; b[SWZ(4*j+3)]=x3;
  x0=b[SWZ(j)]; x1=b[SWZ(j+64)]; x2=b[SWZ(j+128)]; x3=b[SWZ(j+192)];
  radix4_tw<SIGN>(x0,x1,x2,x3, wA);
  { int i=((j>>2)<<4)+(j&3); b[SWZ(i)]=x0; b[SWZ(i+4)]=x1; b[SWZ(i+8)]=x2; b[SWZ(i+12)]=x3; }
  x0=b[SWZ(j)]; x1=b[SWZ(j+64)]; x2=b[SWZ(j+128)]; x3=b[SWZ(j+192)];
  radix4_tw<SIGN>(x0,x1,x2,x3, wB);
  { int i=((j>>4)<<6)+(j&15); b[SWZ(i)]=x0; b[SWZ(i+16)]=x1; b[SWZ(i+32)]=x2; b[SWZ(i+48)]=x3; }
  x0=b[SWZ(j)]; x1=b[SWZ(j+64)]; x2=b[SWZ(j+128)]; x3=b[SWZ(j+192)];
  radix4_tw<SIGN>(x0,x1,x2,x3, wC);
}

// Two independent FFTs, stage-interleaved (r8, verified).
template<int SIGN>
__device__ __forceinline__ void fft256x2(float2* bA, float2* bB, int j,
    float2 wA, float2 wB, float2 wC,
    float2& a0, float2& a1, float2& a2, float2& a3,
    float2& b0, float2& b1, float2& b2, float2& b3){
  radix4_nt<SIGN>(a0,a1,a2,a3); radix4_nt<SIGN>(b0,b1,b2,b3);
  bA[SWZ(4*j)]=a0; bA[SWZ(4*j+1)]=a1; bA[SWZ(4*j+2)]=a2; bA[SWZ(4*j+3)]=a3;
  bB[SWZ(4*j)]=b0; bB[SWZ(4*j+1)]=b1; bB[SWZ(4*j+2)]=b2; bB[SWZ(4*j+3)]=b3;
  a0=bA[SWZ(j)]; a1=bA[SWZ(j+64)]; a2=bA[SWZ(j+128)]; a3=bA[SWZ(j+192)];
  b0=bB[SWZ(j)]; b1=bB[SWZ(j+64)]; b2=bB[SWZ(j+128)]; b3=bB[SWZ(j+192)];
  radix4_tw<SIGN>(a0,a1,a2,a3, wA); radix4_tw<SIGN>(b0,b1,b2,b3, wA);
  { int i=((j>>2)<<4)+(j&3);
    bA[SWZ(i)]=a0; bA[SWZ(i+4)]=a1; bA[SWZ(i+8)]=a2; bA[SWZ(i+12)]=a3;
    bB[SWZ(i)]=b0; bB[SWZ(i+4)]=b1; bB[SWZ(i+8)]=b2; bB[SWZ(i+12)]=b3; }
  a0=bA[SWZ(j)]; a1=bA[SWZ(j+64)]; a2=bA[SWZ(j+128)]; a3=bA[SWZ(j+192)];
  b0=bB[SWZ(j)]; b1=bB[SWZ(j+64)]; b2=bB[SWZ(j+128)]; b3=bB[SWZ(j+192)];
  radix4_tw<SIGN>(a0,a1,a2,a3, wB); radix4_tw<SIGN>(b0,b1,b2,b3, wB);
  { int i=((j>>4)<<6)+(j&15);
    bA[SWZ(i)]=a0; bA[SWZ(i+16)]=a1; bA[SWZ(i+32)]=a2; bA[SWZ(i+48)]=a3;
    bB[SWZ(i)]=b0; bB[SWZ(i+16)]=b1; bB[SWZ(i+32)]=b2; bB[SWZ(i+48)]=b3; }
  a0=bA[SWZ(j)]; a1=bA[SWZ(j+64)]; a2=bA[SWZ(j+128)]; a3=bA[SWZ(j+192)];
  b0=bB[SWZ(j)]; b1=bB[SWZ(j+64)]; b2=bB[SWZ(j+128)]; b3=bB[SWZ(j+192)];
  radix4_tw<SIGN>(a0,a1,a2,a3, wC); radix4_tw<SIGN>(b0,b1,b2,b3, wC);
}

// Scalar chain: given rs chain rs_0..rs_{n-1} (scal) and the fresh Parseval
// tuple (parR,parI)=par_{n-1}, produce alpha_{n-1}, beta_{n-1}.
// P2 recursion uses exact-CG orthogonality: |p_k|^2 = rs_k + beta_k^2 |p_{k-1}|^2.
__device__ __forceinline__ void cg_chain2(const float* __restrict__ scal, int n,
                                          float parR, float parI,
                                          float& a_re, float& a_im, float& beta){
  float rs0 = scal[0];
  float P2 = rs0, rs_km1 = rs0;
  beta = 0.f;
  for (int k = 1; k < n; k++){
    float rsk = scal[k];
    beta = rsk / rs_km1;
    P2 = rsk + beta*beta*P2;
    rs_km1 = rsk;
  }
  float pr = parR + LAMBDA_F*P2, pi = parI;
  float den = pr*pr + pi*pi;
  a_re =  rs_km1*pr/den;
  a_im = -rs_km1*pi/den;
}

// ---------- S0: W9 precompute + g = D*sum_t conj(L) y (into bufB) + zero scal/part
__global__ __launch_bounds__(256) void k_setup(const float* __restrict__ mask,
                                               const float2* __restrict__ Lt,
                                               const float2* __restrict__ y,
                                               float* __restrict__ W9,
                                               float2* __restrict__ bufB,
                                               float* __restrict__ scal,
                                               float* __restrict__ part){
  int tid = threadIdx.x;
  int u = blockIdx.x;
  if (u == 0){
    if (tid < 128) scal[tid] = 0.0f;
    for (int i = tid; i < NPART_ROWS*1024; i += 256) part[i] = 0.0f;
  }
  if (u < 256){
    int kx = u, ky = tid;
    int mx = (kx + 128) & 255, my = (ky + 128) & 255;
    float d0=0.f,d1=0.f,d2=0.f;
    float2 o01=make_float2(0,0), o02=make_float2(0,0), o12=make_float2(0,0);
    for (int t = 0; t < NT; t++){
      float m = mask[t*HW + my*256 + mx];
      float2 l0 = Lt[t*3+0], l1 = Lt[t*3+1], l2 = Lt[t*3+2];
      d0 += m*(l0.x*l0.x + l0.y*l0.y);
      d1 += m*(l1.x*l1.x + l1.y*l1.y);
      d2 += m*(l2.x*l2.x + l2.y*l2.y);
      o01 = cadd(o01, cscale(cmulj(l0,l1), m));
      o02 = cadd(o02, cscale(cmulj(l0,l2), m));
      o12 = cadd(o12, cscale(cmulj(l1,l2), m));
    }
    const float nrm = 1.0f/65536.0f;
    int idx = kx*256 + ky;
    W9[idx]      = d0*nrm;  W9[idx+HW]   = d1*nrm;  W9[idx+2*HW] = d2*nrm;
    W9[idx+3*HW] = o01.x*nrm; W9[idx+4*HW] = o01.y*nrm;
    W9[idx+5*HW] = o02.x*nrm; W9[idx+6*HW] = o02.y*nrm;
    W9[idx+7*HW] = o12.x*nrm; W9[idx+8*HW] = o12.y*nrm;
  } else {
    int idx = (u-256)*256 + tid;
    int c = idx >> 16, pix = idx & (HW-1);
    int xx = pix & 255, yy2 = pix >> 8;
    float sg = ((xx + yy2) & 1) ? -1.0f : 1.0f;
    float2 a0=make_float2(0,0), a1=make_float2(0,0), a2=make_float2(0,0);
    for (int t = 0; t < NT; t++){
      float2 yv = y[((size_t)(t*NC + c))*HW + pix];
      a0 = cadd(a0, cmulj(Lt[t*3+0], yv));
      a1 = cadd(a1, cmulj(Lt[t*3+1], yv));
      a2 = cadd(a2, cmulj(Lt[t*3+2], yv));
    }
    bufB[((size_t)(c*3+0))*HW + pix] = cscale(a0, sg);
    bufB[((size_t)(c*3+1))*HW + pix] = cscale(a1, sg);
    bufB[((size_t)(c*3+2))*HW + pix] = cscale(a2, sg);
  }
}

// ---------- setup row IFFT (-1): bufB row-major -> bufT transposed [pl][kx][y]
__global__ __launch_bounds__(512) void k_rows_plain(const float2* __restrict__ src,
                                                    float2* __restrict__ dst){
  __shared__ float2 tile[8][256];
  int tid = threadIdx.x, g = tid >> 6, j = tid & 63;
  float2 wA = twf((j&3)<<4), wB = twf((j&15)<<2), wC = twf(j);
  int pl = blockIdx.y, ri = blockIdx.x;
  int row = ri*8 + g;
  const float2* sr = src + (size_t)pl*HW + row*256;
  float2 x0=sr[j], x1=sr[j+64], x2=sr[j+128], x3=sr[j+192];
  fft256<-1>(tile[g], j, wA,wB,wC, x0,x1,x2,x3);
  tile[g][j]=x0; tile[g][j+64]=x1; tile[g][j+128]=x2; tile[g][j+192]=x3;
  __syncthreads();
  float2* dT = dst + (size_t)pl*HW;
  int yo2 = (tid&3)*2, kxo = tid>>2;
  #pragma unroll
  for (int kb = 0; kb < 2; kb++){
    int kx = kb*128 + kxo;
    float2 a = tile[yo2][kx], b = tile[yo2+1][kx];
    *(float4*)(dT + (size_t)kx*256 + ri*8 + yo2) = make_float4(a.x,a.y,b.x,b.y);
  }
}

// ---------- setup col IFFT (-1): bufT [pl][kx][y] contiguous -> bufB row-major
__global__ __launch_bounds__(512) void k_cols_plain(const float2* __restrict__ src,
                                                    float2* __restrict__ dst){
  __shared__ float2 tile[8][256];
  int tid = threadIdx.x, g = tid >> 6, j = tid & 63;
  float2 wA = twf((j&3)<<4), wB = twf((j&15)<<2), wC = twf(j);
  int pl = blockIdx.y, kg = blockIdx.x;
  int kx = kg*8 + g;
  const float2* col = src + (size_t)pl*HW + (size_t)kx*256;
  float2 x0=col[j], x1=col[j+64], x2=col[j+128], x3=col[j+192];
  fft256<-1>(tile[g], j, wA,wB,wC, x0,x1,x2,x3);
  tile[g][j]=x0; tile[g][j+64]=x1; tile[g][j+128]=x2; tile[g][j+192]=x3;
  __syncthreads();
  float2* d = dst + (size_t)pl*HW;
  int kxo2 = (tid&3)*2, yy = tid>>2;
  #pragma unroll
  for (int yb = 0; yb < 2; yb++){
    int yc = yb*128 + yy;
    float2 a = tile[kxo2][yc], b = tile[kxo2+1][yc];
    *(float4*)(d + (size_t)yc*256 + kg*8 + kxo2) = make_float4(a.x,a.y,b.x,b.y);
  }
}

// ---------- b = D * sum_c conj(S_c) * bufB + lambda*mo ; r0 = b ; z=0 ; rs0 partial
__global__ __launch_bounds__(256) void k_compute_b(const float2* __restrict__ A,
                                                   const float2* __restrict__ sens,
                                                   const float2* __restrict__ mo,
                                                   float2* __restrict__ r,
                                                   float2* __restrict__ z,
                                                   float* __restrict__ part){
  __shared__ float red[4];
  int idx = blockIdx.x*256 + threadIdx.x;
  int s = idx >> 16, pix = idx & (HW-1);
  int xx = pix & 255, yy = pix >> 8;
  float sg = ((xx + yy) & 1) ? -1.0f : 1.0f;
  float2 accv = make_float2(0,0);
  for (int c = 0; c < NC; c++)
    accv = cadd(accv, cmulj(sens[(size_t)c*HW + pix], A[((size_t)(c*3+s))*HW + pix]));
  float2 b = cadd(cscale(accv, sg), cscale(mo[idx], LAMBDA_F));
  r[idx] = b; z[idx] = make_float2(0,0);
  float partv = b.x*b.x + b.y*b.y;
  for (int off = 32; off; off >>= 1) partv += __shfl_down(partv, off);
  int j = threadIdx.x & 63, w = threadIdx.x >> 6;
  if (j == 0) red[w] = partv;
  __syncthreads();
  if (threadIdx.x == 0) part[ROW_RS(0)*1024 + blockIdx.x] = red[0]+red[1]+red[2]+red[3];
}

// ---------- BIG-ROW kernel. grid (256 rows, 3 s), 640 thr = 10 waves (wave = coil).
// MODE 0 (iter=0): stage r0 row, FFT S_c*r0 -> bufR row-major.
// MODE 1 (iter>=1): finish A p_{it-1}: IFFT bufB rows + conj(S) combine;
//   p_{it-1} = r_{it-1} + beta*p_{it-2}; Ap = M + lambda*p; z += alpha*p;
//   r_it = r_{it-1} - alpha*Ap (in place); reduce rs_it; FFT S_c*r_it -> bufR.
template<int MODE>
__global__ __launch_bounds__(640) void k_bigrow(const float2* __restrict__ bufB,
                                                const float2* __restrict__ sens,
                                                float2* __restrict__ rbuf,
                                                float2* __restrict__ pbuf,
                                                float2* __restrict__ zbuf,
                                                float2* __restrict__ bufR,
                                                const float* __restrict__ scal,
                                                float* __restrict__ part, int iter){
  __shared__ float2 scratch[10][256];
  __shared__ float2 rnew_s[256];
  __shared__ float redv[10];
  __shared__ float sA[2];
  int tid = threadIdx.x, w = tid >> 6, j = tid & 63;
  float2 wA = twf((j&3)<<4), wB = twf((j&15)<<2), wC = twf(j);
  int row = blockIdx.x, s = blockIdx.y;

  if constexpr (MODE == 1){
    // --- reconstruct alpha_{iter-1}, beta_{iter-1}
    #pragma unroll
    for (int q = 0; q < 2; q++){
      const float* P = part + (ROW_PAR(iter-1)+q)*1024;
      float v = P[tid] + ((tid < 384) ? P[tid+640] : 0.f);
      for (int off = 32; off; off >>= 1) v += __shfl_down(v, off);
      if (j == 0) redv[w] = v;
      __syncthreads();
      if (tid == 0){
        float t = 0.f;
        #pragma unroll
        for (int k = 0; k < 10; k++) t += redv[k];
        sA[q] = t;
      }
      __syncthreads();
    }
    float a_re, a_im, beta;
    cg_chain2(scal, iter, sA[0], sA[1], a_re, a_im, beta);

    // --- phase 1: row IFFT of bufB per coil + conj(S)
    {
      int c = w;
      const float2* src = bufB + ((size_t)(c*3+s))*HW + row*256;
      float2 x0=src[j], x1=src[j+64], x2=src[j+128], x3=src[j+192];
      fft256<-1>(scratch[c], j, wA,wB,wC, x0,x1,x2,x3);
      const float2* Sc = sens + (size_t)c*HW + row*256;
      scratch[c][j]     = cmulj(Sc[j],     x0);
      scratch[c][j+64]  = cmulj(Sc[j+64],  x1);
      scratch[c][j+128] = cmulj(Sc[j+128], x2);
      scratch[c][j+192] = cmulj(Sc[j+192], x3);
    }
    __syncthreads();
    // --- phase 2: combine + CG updates (threads 0..255)
    if (tid < 256){
      int k = tid;
      float2 M = make_float2(0,0);
      #pragma unroll
      for (int c = 0; c < NC; c++) M = cadd(M, scratch[c][k]);
      size_t ob = (size_t)s*HW + row*256 + k;
      float2 rold = rbuf[ob];
      float2 pcur;
      if (iter == 1) pcur = rold;
      else { float2 pold = pbuf[ob]; pcur = cadd(rold, cscale(pold, beta)); }
      float2 Ap = cadd(M, cscale(pcur, LAMBDA_F));
      float2 rnew = make_float2(rold.x - (a_re*Ap.x - a_im*Ap.y),
                                rold.y - (a_re*Ap.y + a_im*Ap.x));
      float2 zo = zbuf[ob];
      zbuf[ob] = make_float2(zo.x + a_re*pcur.x - a_im*pcur.y,
                             zo.y + a_re*pcur.y + a_im*pcur.x);
      pbuf[ob] = pcur;
      rbuf[ob] = rnew;
      rnew_s[k] = rnew;
      float pv2 = rnew.x*rnew.x + rnew.y*rnew.y;
      for (int off = 32; off; off >>= 1) pv2 += __shfl_down(pv2, off);
      if (j == 0) redv[w] = pv2;   // w in 0..3 here
    }
    __syncthreads();
    if (tid == 0)
      part[ROW_RS(iter)*1024 + s*256 + row] = redv[0]+redv[1]+redv[2]+redv[3];
  } else {
    // MODE 0: stage r0 row
    if (tid < 256){
      size_t ob = (size_t)s*HW + row*256 + tid;
      rnew_s[tid] = rbuf[ob];
    }
    __syncthreads();
  }

  // --- phase 3: FFT S_c * r_new -> bufR row-major (coalesced)
  {
    int c = w;
    const float2* Sc = sens + (size_t)c*HW + row*256;
    float2 x0 = cmul(Sc[j],     rnew_s[j]);
    float2 x1 = cmul(Sc[j+64],  rnew_s[j+64]);
    float2 x2 = cmul(Sc[j+128], rnew_s[j+128]);
    float2 x3 = cmul(Sc[j+192], rnew_s[j+192]);
    fft256<1>(scratch[c], j, wA,wB,wC, x0,x1,x2,x3);
    float2* d = bufR + ((size_t)(c*3+s))*HW + row*256;
    d[j]=x0; d[j+64]=x1; d[j+128]=x2; d[j+192]=x3;
  }
}

// ---------- COL kernel: gather bufR rows -> col FFT(+1) -> Kp = Kr + beta*Kp
// -> U = W*Kp (+ Parseval pAp partials) -> col IFFT(-1) -> scatter bufB row-major.
// grid (64 kx-groups of 4, 10 c), 384 thr = 6 waves: wave w -> (s=w>>1, kx pair).
__global__ __launch_bounds__(384) void k_colW(const float2* __restrict__ bufR,
                                              float2* __restrict__ Kp,
                                              float2* __restrict__ bufB,
                                              const float* __restrict__ W9,
                                              float* __restrict__ scal,
                                              float* __restrict__ part, int iter){
  __shared__ float2 T[12][256];
  __shared__ float redv[6][2];
  __shared__ float sB[1];
  int tid = threadIdx.x, w = tid >> 6, j = tid & 63;
  float2 wA = twf((j&3)<<4), wB = twf((j&15)<<2), wC = twf(j);
  int kg = blockIdx.x, c = blockIdx.y;
  int s = w >> 1, kxp = w & 1;
  int kxl0 = kxp*2, kxl1 = kxl0 + 1;
  int kx0 = kg*4 + kxl0, kx1 = kg*4 + kxl1;

  // --- rs_iter re-reduce (row iter) + beta
  float rs_it;
  {
    const float* P = part + ROW_RS(iter)*1024;
    float v = P[tid] + P[tid+384] + ((tid < 256) ? P[tid+768] : 0.f);
    for (int off = 32; off; off >>= 1) v += __shfl_down(v, off);
    if (j == 0) redv[w][0] = v;
    __syncthreads();
    if (tid == 0){
      float t = 0.f;
      #pragma unroll
      for (int k = 0; k < 6; k++) t += redv[k][0];
      sB[0] = t;
    }
    __syncthreads();
    rs_it = sB[0];
  }
  float beta = (iter == 0) ? 0.f : rs_it / scal[iter-1];
  if (blockIdx.x == 0 && blockIdx.y == 0 && tid == 0) scal[iter] = rs_it;

  // --- gather bufR (row-major) 3 planes x 4 cols into T
  #pragma unroll
  for (int f = 0; f < 4; f++){
    int idx = f*384 + tid;            // 0..1535
    int sp = idx >> 9, rem = idx & 511, rrow = rem >> 1, cp = rem & 1;
    const float4* s4 = (const float4*)(bufR + ((size_t)(c*3+sp))*HW);
    float4 v = s4[(size_t)rrow*128 + kg*2 + cp];
    T[sp*4 + cp*2 + 0][rrow] = make_float2(v.x, v.y);
    T[sp*4 + cp*2 + 1][rrow] = make_float2(v.z, v.w);
  }
  __syncthreads();

  // --- col FFT(+1), 2 columns per wave
  float2 a0=T[s*4+kxl0][j], a1=T[s*4+kxl0][j+64], a2=T[s*4+kxl0][j+128], a3=T[s*4+kxl0][j+192];
  float2 b0=T[s*4+kxl1][j], b1=T[s*4+kxl1][j+64], b2=T[s*4+kxl1][j+128], b3=T[s*4+kxl1][j+192];
  fft256x2<1>(T[s*4+kxl0], T[s*4+kxl1], j, wA,wB,wC, a0,a1,a2,a3, b0,b1,b2,b3);

  // --- Kp combine: V = Kr + beta*Kp_old ; store Kp = V (transposed-private layout)
  float2* kpA = Kp + ((size_t)(c*3+s))*HW + (size_t)kx0*256;
  float2* kpB = Kp + ((size_t)(c*3+s))*HW + (size_t)kx1*256;
  if (iter > 0){
    a0 = cadd(a0, cscale(kpA[j],     beta));
    a1 = cadd(a1, cscale(kpA[j+64],  beta));
    a2 = cadd(a2, cscale(kpA[j+128], beta));
    a3 = cadd(a3, cscale(kpA[j+192], beta));
    b0 = cadd(b0, cscale(kpB[j],     beta));
    b1 = cadd(b1, cscale(kpB[j+64],  beta));
    b2 = cadd(b2, cscale(kpB[j+128], beta));
    b3 = cadd(b3, cscale(kpB[j+192], beta));
  }
  kpA[j]=a0; kpA[j+64]=a1; kpA[j+128]=a2; kpA[j+192]=a3;
  kpB[j]=b0; kpB[j+64]=b1; kpB[j+128]=b2; kpB[j+192]=b3;
  T[s*4+kxl0][j]=a0; T[s*4+kxl0][j+64]=a1; T[s*4+kxl0][j+128]=a2; T[s*4+kxl0][j+192]=a3;
  T[s*4+kxl1][j]=b0; T[s*4+kxl1][j+64]=b1; T[s*4+kxl1][j+128]=b2; T[s*4+kxl1][j+192]=b3;
  __syncthreads();

  // --- U = G(V) + Parseval partials
  float2 UA[4], UB[4];
  float pr = 0.f, pim = 0.f;
  #pragma unroll
  for (int q = 0; q < 4; q++){
    int k = j + 64*q;
    {
      int wi = kx0*256 + k;
      float2 v0 = T[0+kxl0][k], v1 = T[4+kxl0][k], v2 = T[8+kxl0][k];
      float2 U;
      if (s == 0){
        float d0 = W9[wi];
        float2 o01 = make_float2(W9[wi+3*HW], W9[wi+4*HW]);
        float2 o02 = make_float2(W9[wi+5*HW], W9[wi+6*HW]);
        U = cadd(cadd(cscale(v0,d0), cmul(o01,v1)), cmul(o02,v2));
      } else if (s == 1){
        float d1 = W9[wi+HW];
        float2 o01 = make_float2(W9[wi+3*HW], W9[wi+4*HW]);
        float2 o12 = make_float2(W9[wi+7*HW], W9[wi+8*HW]);
        U = cadd(cadd(cmulj(o01,v0), cscale(v1,d1)), cmul(o12,v2));
      } else {
        float d2 = W9[wi+2*HW];
        float2 o02 = make_float2(W9[wi+5*HW], W9[wi+6*HW]);
        float2 o12 = make_float2(W9[wi+7*HW], W9[wi+8*HW]);
        U = cadd(cadd(cmulj(o02,v0), cmulj(o12,v1)), cscale(v2,d2));
      }
      UA[q] = U;
      float2 vs = (s==0) ? v0 : ((s==1) ? v1 : v2);
      pr  += vs.x*U.x + vs.y*U.y;
      pim += vs.x*U.y - vs.y*U.x;
    }
    {
      int wi = kx1*256 + k;
      float2 v0 = T[0+kxl1][k], v1 = T[4+kxl1][k], v2 = T[8+kxl1][k];
      float2 U;
      if (s == 0){
        float d0 = W9[wi];
        float2 o01 = make_float2(W9[wi+3*HW], W9[wi+4*HW]);
        float2 o02 = make_float2(W9[wi+5*HW], W9[wi+6*HW]);
        U = cadd(cadd(cscale(v0,d0), cmul(o01,v1)), cmul(o02,v2));
      } else if (s == 1){
        float d1 = W9[wi+HW];
        float2 o01 = make_float2(W9[wi+3*HW], W9[wi+4*HW]);
        float2 o12 = make_float2(W9[wi+7*HW], W9[wi+8*HW]);
        U = cadd(cadd(cmulj(o01,v0), cscale(v1,d1)), cmul(o12,v2));
      } else {
        float d2 = W9[wi+2*HW];
        float2 o02 = make_float2(W9[wi+5*HW], W9[wi+6*HW]);
        float2 o12 = make_float2(W9[wi+7*HW], W9[wi+8*HW]);
        U = cadd(cadd(cmulj(o02,v0), cmulj(o12,v1)), cscale(v2,d2));
      }
      UB[q] = U;
      float2 vs = (s==0) ? v0 : ((s==1) ? v1 : v2);
      pr  += vs.x*U.x + vs.y*U.y;
      pim += vs.x*U.y - vs.y*U.x;
    }
  }
  __syncthreads();   // all V reads done before T reused as IFFT scratch

  // --- col IFFT(-1)
  {
    float2 c0=UA[0], c1=UA[1], c2=UA[2], c3=UA[3];
    float2 d0=UB[0], d1=UB[1], d2=UB[2], d3=UB[3];
    fft256x2<-1>(T[s*4+kxl0], T[s*4+kxl1], j, wA,wB,wC, c0,c1,c2,c3, d0,d1,d2,d3);
    T[s*4+kxl0][j]=c0; T[s*4+kxl0][j+64]=c1; T[s*4+kxl0][j+128]=c2; T[s*4+kxl0][j+192]=c3;
    T[s*4+kxl1][j]=d0; T[s*4+kxl1][j+64]=d1; T[s*4+kxl1][j+128]=d2; T[s*4+kxl1][j+192]=d3;
  }
  // par wave-reduce (registers only)
  for (int off = 32; off; off >>= 1){
    pr  += __shfl_down(pr, off);
    pim += __shfl_down(pim, off);
  }
  if (j == 0){ redv[w][0] = pr; redv[w][1] = pim; }
  __syncthreads();
  if (tid == 0){
    float tr = 0.f, ti = 0.f;
    #pragma unroll
    for (int k = 0; k < 6; k++){ tr += redv[k][0]; ti += redv[k][1]; }
    int bflat = c*64 + kg;   // 0..639
    part[ ROW_PAR(iter)   *1024 + bflat] = tr;
    part[(ROW_PAR(iter)+1)*1024 + bflat] = ti;
  }
  // --- scatter to bufB row-major
  #pragma unroll
  for (int yb = 0; yb < 4; yb++){
    int flat = yb*384 + tid;
    int s_out = flat >> 9;
    int rem = flat & 511;
    int kxo2 = (rem >> 8) << 1;
    int yc = rem & 255;
    float2 a = T[s_out*4+kxo2][yc], b = T[s_out*4+kxo2+1][yc];
    float2* d = bufB + ((size_t)(c*3+s_out))*HW;
    *(float4*)(d + (size_t)yc*256 + kg*4 + kxo2) = make_float4(a.x,a.y,b.x,b.y);
  }
}

// ---------- final: p9 = r9 + beta9*p8 ; z += alpha9*p9
__global__ __launch_bounds__(256) void k_final(float2* __restrict__ z,
                                               const float2* __restrict__ rbuf,
                                               const float2* __restrict__ pbuf,
                                               const float* __restrict__ scal,
                                               const float* __restrict__ part){
  __shared__ float redv[4];
  __shared__ float sA[2];
  int tid = threadIdx.x, w = tid >> 6, j = tid & 63;
  #pragma unroll
  for (int q = 0; q < 2; q++){
    const float* P = part + (ROW_PAR(9)+q)*1024;
    float v = P[tid] + P[tid+256] + P[tid+512] + P[tid+768];
    for (int off = 32; off; off >>= 1) v += __shfl_down(v, off);
    if (j == 0) redv[w] = v;
    __syncthreads();
    if (tid == 0) sA[q] = redv[0]+redv[1]+redv[2]+redv[3];
    __syncthreads();
  }
  float a_re, a_im, beta;
  cg_chain2(scal, 10, sA[0], sA[1], a_re, a_im, beta);
  int idx = blockIdx.x*256 + tid;
  float2 r9 = rbuf[idx], p8 = pbuf[idx];
  float2 p9 = cadd(r9, cscale(p8, beta));
  float2 zo = z[idx];
  z[idx] = make_float2(zo.x + a_re*p9.x - a_im*p9.y,
                       zo.y + a_re*p9.y + a_im*p9.x);
}

extern "C" void kernel_launch(void* const* d_in, const int* in_sizes, int n_in,
                              void* d_out, int out_size, void* d_ws, size_t ws_size,
                              hipStream_t stream){
  const float2* y    = (const float2*)d_in[0];
  const float2* mo   = (const float2*)d_in[1];
  const float2* sens = (const float2*)d_in[2];
  const float2* Lt   = (const float2*)d_in[3];
  const float*  mask = (const float*)d_in[4];

  float* w = (float*)d_ws;
  float*  scal = w;                                   // 128 floats
  float*  part = w + 128;                             // 36*1024 floats
  float*  W9   = part + NPART_ROWS*1024;              // 9*HW floats
  float2* bufB = (float2*)(W9 + 9*HW);                // 30 planes row-major
  float2* bufR = bufB + (size_t)30*HW;                // 30 planes (row-major k_x rows / setup transpose)
  float2* Kp   = bufR + (size_t)30*HW;                // 30 planes [pl][kx][y] (COL-private)
  float2* rb   = Kp + (size_t)30*HW;                  // 3 planes residual
  float2* pb   = rb + (size_t)3*HW;                   // 3 planes direction
  float2* z    = (float2*)d_out;

  // setup: b-vector via adjoint path (verified r4-r8 kernels)
  k_setup<<<2816, 256, 0, stream>>>(mask, Lt, y, W9, bufB, scal, part);
  k_rows_plain<<<dim3(32, 30), 512, 0, stream>>>(bufB, bufR);
  k_cols_plain<<<dim3(32, 30), 512, 0, stream>>>(bufR, bufB);
  k_compute_b<<<768, 256, 0, stream>>>(bufB, sens, mo, rb, z, part);

  // r0 -> k-space rows
  k_bigrow<0><<<dim3(256, 3), 640, 0, stream>>>(bufB, sens, rb, pb, z, bufR, scal, part, 0);

  // CG loop: 2 kernels per iteration
  for (int it = 0; it < 10; it++){
    if (it > 0)
      k_bigrow<1><<<dim3(256, 3), 640, 0, stream>>>(bufB, sens, rb, pb, z, bufR, scal, part, it);
    k_colW<<<dim3(64, 10), 384, 0, stream>>>(bufR, Kp, bufB, W9, scal, part, it);
  }
  k_final<<<768, 256, 0, stream>>>(z, rb, pb, scal, part);
}

// Round 10
// 529.506 us; speedup vs baseline: 1.2181x; 1.2181x over previous
//
#include <hip/hip_runtime.h>
#include <math.h>

#define HW 65536
#define NC 10
#define NT 12
#define LAMBDA_F 0.05f
#define PI_F 3.14159265358979323846f
// XOR-swizzle for wave-private LDS fft scratch
#define SWZ(i) ((i) ^ ((i) >> 4))
// part buffer rows (1024 floats each)
#define ROW_RS(it)  (it)            // rs_it partials: rows 0..9 (768 entries)
#define ROW_RMR(it) (16 + (it))     // rMr_it partials: rows 16..25 (320 entries)
#define NPART_ROWS 26

__device__ __forceinline__ float2 cadd(float2 a, float2 b){ return make_float2(a.x+b.x, a.y+b.y); }
__device__ __forceinline__ float2 csub(float2 a, float2 b){ return make_float2(a.x-b.x, a.y-b.y); }
__device__ __forceinline__ float2 cmul(float2 a, float2 b){ return make_float2(a.x*b.x-a.y*b.y, a.x*b.y+a.y*b.x); }
// conj(a)*b
__device__ __forceinline__ float2 cmulj(float2 a, float2 b){ return make_float2(a.x*b.x+a.y*b.y, a.x*b.y-a.y*b.x); }
__device__ __forceinline__ float2 cscale(float2 a, float s){ return make_float2(a.x*s, a.y*s); }

template<int SIGN>
__device__ __forceinline__ void radix4_nt(float2& a0, float2& a1, float2& a2, float2& a3){
  float2 t0=cadd(a0,a2), t1=csub(a0,a2), t2=cadd(a1,a3), t3=csub(a1,a3);
  float2 t3r;
  if constexpr (SIGN < 0) t3r = make_float2(t3.y, -t3.x); else t3r = make_float2(-t3.y, t3.x);
  a0=cadd(t0,t2); a1=cadd(t1,t3r); a2=csub(t0,t2); a3=csub(t1,t3r);
}

template<int SIGN>
__device__ __forceinline__ void radix4_tw(float2& a0, float2& a1, float2& a2, float2& a3, float2 w){
  if constexpr (SIGN > 0) w.y = -w.y;
  float2 w2 = cmul(w, w);
  float2 w3 = cmul(w, w2);
  a1 = cmul(a1, w); a2 = cmul(a2, w2); a3 = cmul(a3, w3);
  radix4_nt<SIGN>(a0, a1, a2, a3);
}

__device__ __forceinline__ float2 twf(int e){
  float s, c;
  __sincosf(-2.0f*PI_F*(float)e*(1.0f/256.0f), &s, &c);
  return make_float2(c, s);
}

// Single 256-pt Stockham radix-4 FFT, wave-private scratch b.
template<int SIGN>
__device__ __forceinline__ void fft256(float2* b, int j,
                                       float2 wA, float2 wB, float2 wC,
                                       float2& x0, float2& x1, float2& x2, float2& x3){
  radix4_nt<SIGN>(x0,x1,x2,x3);
  b[SWZ(4*j)]=x0; b[SWZ(4*j+1)]=x1; b[SWZ(4*j+2)]=x2; b[SWZ(4*j+3)]=x3;
  x0=b[SWZ(j)]; x1=b[SWZ(j+64)]; x2=b[SWZ(j+128)]; x3=b[SWZ(j+192)];
  radix4_tw<SIGN>(x0,x1,x2,x3, wA);
  { int i=((j>>2)<<4)+(j&3); b[SWZ(i)]=x0; b[SWZ(i+4)]=x1; b[SWZ(i+8)]=x2; b[SWZ(i+12)]=x3; }
  x0=b[SWZ(j)]; x1=b[SWZ(j+64)]; x2=b[SWZ(j+128)]; x3=b[SWZ(j+192)];
  radix4_tw<SIGN>(x0,x1,x2,x3, wB);
  { int i=((j>>4)<<6)+(j&15); b[SWZ(i)]=x0; b[SWZ(i+16)]=x1; b[SWZ(i+32)]=x2; b[SWZ(i+48)]=x3; }
  x0=b[SWZ(j)]; x1=b[SWZ(j+64)]; x2=b[SWZ(j+128)]; x3=b[SWZ(j+192)];
  radix4_tw<SIGN>(x0,x1,x2,x3, wC);
}

// Two independent FFTs, stage-interleaved (r8/r9, verified).
template<int SIGN>
__device__ __forceinline__ void fft256x2(float2* bA, float2* bB, int j,
    float2 wA, float2 wB, float2 wC,
    float2& a0, float2& a1, float2& a2, float2& a3,
    float2& b0, float2& b1, float2& b2, float2& b3){
  radix4_nt<SIGN>(a0,a1,a2,a3); radix4_nt<SIGN>(b0,b1,b2,b3);
  bA[SWZ(4*j)]=a0; bA[SWZ(4*j+1)]=a1; bA[SWZ(4*j+2)]=a2; bA[SWZ(4*j+3)]=a3;
  bB[SWZ(4*j)]=b0; bB[SWZ(4*j+1)]=b1; bB[SWZ(4*j+2)]=b2; bB[SWZ(4*j+3)]=b3;
  a0=bA[SWZ(j)]; a1=bA[SWZ(j+64)]; a2=bA[SWZ(j+128)]; a3=bA[SWZ(j+192)];
  b0=bB[SWZ(j)]; b1=bB[SWZ(j+64)]; b2=bB[SWZ(j+128)]; b3=bB[SWZ(j+192)];
  radix4_tw<SIGN>(a0,a1,a2,a3, wA); radix4_tw<SIGN>(b0,b1,b2,b3, wA);
  { int i=((j>>2)<<4)+(j&3);
    bA[SWZ(i)]=a0; bA[SWZ(i+4)]=a1; bA[SWZ(i+8)]=a2; bA[SWZ(i+12)]=a3;
    bB[SWZ(i)]=b0; bB[SWZ(i+4)]=b1; bB[SWZ(i+8)]=b2; bB[SWZ(i+12)]=b3; }
  a0=bA[SWZ(j)]; a1=bA[SWZ(j+64)]; a2=bA[SWZ(j+128)]; a3=bA[SWZ(j+192)];
  b0=bB[SWZ(j)]; b1=bB[SWZ(j+64)]; b2=bB[SWZ(j+128)]; b3=bB[SWZ(j+192)];
  radix4_tw<SIGN>(a0,a1,a2,a3, wB); radix4_tw<SIGN>(b0,b1,b2,b3, wB);
  { int i=((j>>4)<<6)+(j&15);
    bA[SWZ(i)]=a0; bA[SWZ(i+16)]=a1; bA[SWZ(i+32)]=a2; bA[SWZ(i+48)]=a3;
    bB[SWZ(i)]=b0; bB[SWZ(i+16)]=b1; bB[SWZ(i+32)]=b2; bB[SWZ(i+48)]=b3; }
  a0=bA[SWZ(j)]; a1=bA[SWZ(j+64)]; a2=bA[SWZ(j+128)]; a3=bA[SWZ(j+192)];
  b0=bB[SWZ(j)]; b1=bB[SWZ(j+64)]; b2=bB[SWZ(j+128)]; b3=bB[SWZ(j+192)];
  radix4_tw<SIGN>(a0,a1,a2,a3, wC); radix4_tw<SIGN>(b0,b1,b2,b3, wC);
}

// Exact-CG scalar chain (Hermitian M -> all scalars real):
//   beta_k = rs_k/rs_{k-1}
//   mp_k   = <p_k,M p_k> = rMr_k - 2 beta_k rs_k / alpha_{k-1} + beta_k^2 mp_{k-1}
//   P2_k   = |p_k|^2     = rs_k + beta_k^2 P2_{k-1}
//   pAp_k  = mp_k + lambda P2_k ;  alpha_k = rs_k / pAp_k
// scal[k] = rs_k (k <= n-2), scal[32+k] = rMr_k; freshest pair passed in regs.
__device__ __forceinline__ void cg_chain3(const float* __restrict__ scal, int n,
                                          float rs_f, float rmr_f,
                                          float& alpha, float& beta){
  float mp = 0.f, P2 = 0.f, rs_prev = 1.f;
  alpha = 0.f; beta = 0.f;
  for (int k = 0; k < n; k++){
    float rsk  = (k == n-1) ? rs_f  : scal[k];
    float rmrk = (k == n-1) ? rmr_f : scal[32+k];
    if (k == 0){ beta = 0.f; mp = rmrk; P2 = rsk; }
    else {
      beta = rsk / rs_prev;
      mp = rmrk - 2.f*beta*rsk/alpha + beta*beta*mp;
      P2 = rsk + beta*beta*P2;
    }
    float pap = mp + LAMBDA_F*P2;
    alpha = rsk / pap;
    rs_prev = rsk;
  }
}

// W-combine for one output plane s (wave-uniform s -> no divergence)
__device__ __forceinline__ float2 w_combine(const float* __restrict__ W9, int wi, int s,
                                            float2 v0, float2 v1, float2 v2){
  if (s == 0){
    float d0 = W9[wi];
    float2 o01 = make_float2(W9[wi+3*HW], W9[wi+4*HW]);
    float2 o02 = make_float2(W9[wi+5*HW], W9[wi+6*HW]);
    return cadd(cadd(cscale(v0,d0), cmul(o01,v1)), cmul(o02,v2));
  } else if (s == 1){
    float d1 = W9[wi+HW];
    float2 o01 = make_float2(W9[wi+3*HW], W9[wi+4*HW]);
    float2 o12 = make_float2(W9[wi+7*HW], W9[wi+8*HW]);
    return cadd(cadd(cmulj(o01,v0), cscale(v1,d1)), cmul(o12,v2));
  } else {
    float d2 = W9[wi+2*HW];
    float2 o02 = make_float2(W9[wi+5*HW], W9[wi+6*HW]);
    float2 o12 = make_float2(W9[wi+7*HW], W9[wi+8*HW]);
    return cadd(cadd(cmulj(o02,v0), cmulj(o12,v1)), cscale(v2,d2));
  }
}

// ---------- S0: W9 precompute + g = D*sum_t conj(L) y (into bufB) + zero scal/part
__global__ __launch_bounds__(256) void k_setup(const float* __restrict__ mask,
                                               const float2* __restrict__ Lt,
                                               const float2* __restrict__ y,
                                               float* __restrict__ W9,
                                               float2* __restrict__ bufB,
                                               float* __restrict__ scal,
                                               float* __restrict__ part){
  int tid = threadIdx.x;
  int u = blockIdx.x;
  if (u == 0){
    if (tid < 128) scal[tid] = 0.0f;
    for (int i = tid; i < NPART_ROWS*1024; i += 256) part[i] = 0.0f;
  }
  if (u < 256){
    int kx = u, ky = tid;
    int mx = (kx + 128) & 255, my = (ky + 128) & 255;
    float d0=0.f,d1=0.f,d2=0.f;
    float2 o01=make_float2(0,0), o02=make_float2(0,0), o12=make_float2(0,0);
    for (int t = 0; t < NT; t++){
      float m = mask[t*HW + my*256 + mx];
      float2 l0 = Lt[t*3+0], l1 = Lt[t*3+1], l2 = Lt[t*3+2];
      d0 += m*(l0.x*l0.x + l0.y*l0.y);
      d1 += m*(l1.x*l1.x + l1.y*l1.y);
      d2 += m*(l2.x*l2.x + l2.y*l2.y);
      o01 = cadd(o01, cscale(cmulj(l0,l1), m));
      o02 = cadd(o02, cscale(cmulj(l0,l2), m));
      o12 = cadd(o12, cscale(cmulj(l1,l2), m));
    }
    const float nrm = 1.0f/65536.0f;
    int idx = kx*256 + ky;
    W9[idx]      = d0*nrm;  W9[idx+HW]   = d1*nrm;  W9[idx+2*HW] = d2*nrm;
    W9[idx+3*HW] = o01.x*nrm; W9[idx+4*HW] = o01.y*nrm;
    W9[idx+5*HW] = o02.x*nrm; W9[idx+6*HW] = o02.y*nrm;
    W9[idx+7*HW] = o12.x*nrm; W9[idx+8*HW] = o12.y*nrm;
  } else {
    int idx = (u-256)*256 + tid;
    int c = idx >> 16, pix = idx & (HW-1);
    int xx = pix & 255, yy2 = pix >> 8;
    float sg = ((xx + yy2) & 1) ? -1.0f : 1.0f;
    float2 a0=make_float2(0,0), a1=make_float2(0,0), a2=make_float2(0,0);
    for (int t = 0; t < NT; t++){
      float2 yv = y[((size_t)(t*NC + c))*HW + pix];
      a0 = cadd(a0, cmulj(Lt[t*3+0], yv));
      a1 = cadd(a1, cmulj(Lt[t*3+1], yv));
      a2 = cadd(a2, cmulj(Lt[t*3+2], yv));
    }
    bufB[((size_t)(c*3+0))*HW + pix] = cscale(a0, sg);
    bufB[((size_t)(c*3+1))*HW + pix] = cscale(a1, sg);
    bufB[((size_t)(c*3+2))*HW + pix] = cscale(a2, sg);
  }
}

// ---------- setup row IFFT (-1): bufB row-major -> bufR transposed [pl][kx][y]
__global__ __launch_bounds__(512) void k_rows_plain(const float2* __restrict__ src,
                                                    float2* __restrict__ dst){
  __shared__ float2 tile[8][256];
  int tid = threadIdx.x, g = tid >> 6, j = tid & 63;
  float2 wA = twf((j&3)<<4), wB = twf((j&15)<<2), wC = twf(j);
  int pl = blockIdx.y, ri = blockIdx.x;
  int row = ri*8 + g;
  const float2* sr = src + (size_t)pl*HW + row*256;
  float2 x0=sr[j], x1=sr[j+64], x2=sr[j+128], x3=sr[j+192];
  fft256<-1>(tile[g], j, wA,wB,wC, x0,x1,x2,x3);
  tile[g][j]=x0; tile[g][j+64]=x1; tile[g][j+128]=x2; tile[g][j+192]=x3;
  __syncthreads();
  float2* dT = dst + (size_t)pl*HW;
  int yo2 = (tid&3)*2, kxo = tid>>2;
  #pragma unroll
  for (int kb = 0; kb < 2; kb++){
    int kx = kb*128 + kxo;
    float2 a = tile[yo2][kx], b = tile[yo2+1][kx];
    *(float4*)(dT + (size_t)kx*256 + ri*8 + yo2) = make_float4(a.x,a.y,b.x,b.y);
  }
}

// ---------- setup col IFFT (-1): bufR [pl][kx][y] contiguous -> bufB row-major
__global__ __launch_bounds__(512) void k_cols_plain(const float2* __restrict__ src,
                                                    float2* __restrict__ dst){
  __shared__ float2 tile[8][256];
  int tid = threadIdx.x, g = tid >> 6, j = tid & 63;
  float2 wA = twf((j&3)<<4), wB = twf((j&15)<<2), wC = twf(j);
  int pl = blockIdx.y, kg = blockIdx.x;
  int kx = kg*8 + g;
  const float2* col = src + (size_t)pl*HW + (size_t)kx*256;
  float2 x0=col[j], x1=col[j+64], x2=col[j+128], x3=col[j+192];
  fft256<-1>(tile[g], j, wA,wB,wC, x0,x1,x2,x3);
  tile[g][j]=x0; tile[g][j+64]=x1; tile[g][j+128]=x2; tile[g][j+192]=x3;
  __syncthreads();
  float2* d = dst + (size_t)pl*HW;
  int kxo2 = (tid&3)*2, yy = tid>>2;
  #pragma unroll
  for (int yb = 0; yb < 2; yb++){
    int yc = yb*128 + yy;
    float2 a = tile[kxo2][yc], b = tile[kxo2+1][yc];
    *(float4*)(d + (size_t)yc*256 + kg*8 + kxo2) = make_float4(a.x,a.y,b.x,b.y);
  }
}

// ---------- b = D * sum_c conj(S_c) * bufB + lambda*mo ; r0 = b ; z=0 ; rs0 partial
__global__ __launch_bounds__(256) void k_compute_b(const float2* __restrict__ A,
                                                   const float2* __restrict__ sens,
                                                   const float2* __restrict__ mo,
                                                   float2* __restrict__ r,
                                                   float2* __restrict__ z,
                                                   float* __restrict__ part){
  __shared__ float red[4];
  int idx = blockIdx.x*256 + threadIdx.x;
  int s = idx >> 16, pix = idx & (HW-1);
  int xx = pix & 255, yy = pix >> 8;
  float sg = ((xx + yy) & 1) ? -1.0f : 1.0f;
  float2 accv = make_float2(0,0);
  for (int c = 0; c < NC; c++)
    accv = cadd(accv, cmulj(sens[(size_t)c*HW + pix], A[((size_t)(c*3+s))*HW + pix]));
  float2 b = cadd(cscale(accv, sg), cscale(mo[idx], LAMBDA_F));
  r[idx] = b; z[idx] = make_float2(0,0);
  float partv = b.x*b.x + b.y*b.y;
  for (int off = 32; off; off >>= 1) partv += __shfl_down(partv, off);
  int j = threadIdx.x & 63, w = threadIdx.x >> 6;
  if (j == 0) red[w] = partv;
  __syncthreads();
  if (threadIdx.x == 0) part[ROW_RS(0)*1024 + blockIdx.x] = red[0]+red[1]+red[2]+red[3];
}

// ---------- BIG-ROW kernel. grid (256 rows, 3 s), 640 thr = 10 waves (wave = coil).
// MODE 0 (iter=0): stage r0 row, FFT S_c*r0 -> bufR row-major.
// MODE 1 (iter>=1): bufB holds transform of K(S r_{it-1}) -> row-IFFT + combine
//   = Mr_{it-1}. Chain gives alpha_{it-1}, beta_{it-1}. Then:
//   p = r + beta*p_old ; Mp = Mr + beta*Mp_old ; Ap = Mp + lambda p ;
//   z += alpha p ; r_new = r - alpha Ap ; reduce rs_it ; FFT S_c*r_new -> bufR.
template<int MODE>
__global__ __launch_bounds__(640) void k_bigrow(const float2* __restrict__ bufB,
                                                const float2* __restrict__ sens,
                                                float2* __restrict__ rbuf,
                                                float2* __restrict__ pbuf,
                                                float2* __restrict__ Mpb,
                                                float2* __restrict__ zbuf,
                                                float2* __restrict__ bufR,
                                                float* __restrict__ scal,
                                                float* __restrict__ part, int iter){
  __shared__ float2 scratch[10][256];
  __shared__ float2 rnew_s[256];
  __shared__ float redv[10];
  __shared__ float sA[2];
  int tid = threadIdx.x, w = tid >> 6, j = tid & 63;
  float2 wA = twf((j&3)<<4), wB = twf((j&15)<<2), wC = twf(j);
  int row = blockIdx.x, s = blockIdx.y;

  if constexpr (MODE == 1){
    // --- reduce fresh scalar partials: rs_{it-1} (768) and rMr_{it-1} (320)
    int rowsel[2] = { ROW_RS(iter-1), ROW_RMR(iter-1) };
    #pragma unroll
    for (int q = 0; q < 2; q++){
      const float* P = part + rowsel[q]*1024;
      float v = P[tid] + ((tid < 384) ? P[tid+640] : 0.f);
      for (int off = 32; off; off >>= 1) v += __shfl_down(v, off);
      if (j == 0) redv[w] = v;
      __syncthreads();
      if (tid == 0){
        float t = 0.f;
        #pragma unroll
        for (int k = 0; k < 10; k++) t += redv[k];
        sA[q] = t;
      }
      __syncthreads();
    }
    float alpha, beta;
    cg_chain3(scal, iter, sA[0], sA[1], alpha, beta);
    if (blockIdx.x == 0 && blockIdx.y == 0 && tid == 0){
      scal[iter-1]    = sA[0];
      scal[32+iter-1] = sA[1];
    }

    // --- phase 1: row IFFT of bufB per coil + conj(S)
    {
      int c = w;
      const float2* src = bufB + ((size_t)(c*3+s))*HW + row*256;
      float2 x0=src[j], x1=src[j+64], x2=src[j+128], x3=src[j+192];
      fft256<-1>(scratch[c], j, wA,wB,wC, x0,x1,x2,x3);
      const float2* Sc = sens + (size_t)c*HW + row*256;
      scratch[c][j]     = cmulj(Sc[j],     x0);
      scratch[c][j+64]  = cmulj(Sc[j+64],  x1);
      scratch[c][j+128] = cmulj(Sc[j+128], x2);
      scratch[c][j+192] = cmulj(Sc[j+192], x3);
    }
    __syncthreads();
    // --- phase 2: combine -> Mr; CG updates (threads 0..255)
    if (tid < 256){
      int k = tid;
      float2 Mr = make_float2(0,0);
      #pragma unroll
      for (int c = 0; c < NC; c++) Mr = cadd(Mr, scratch[c][k]);
      size_t ob = (size_t)s*HW + row*256 + k;
      float2 rold = rbuf[ob];
      float2 pcur, Mpc;
      if (iter == 1){ pcur = rold; Mpc = Mr; }
      else {
        pcur = cadd(rold, cscale(pbuf[ob], beta));
        Mpc  = cadd(Mr,   cscale(Mpb[ob],  beta));
      }
      Mpb[ob]  = Mpc;
      pbuf[ob] = pcur;
      float2 Ap = cadd(Mpc, cscale(pcur, LAMBDA_F));
      float2 zo = zbuf[ob];
      zbuf[ob] = make_float2(zo.x + alpha*pcur.x, zo.y + alpha*pcur.y);
      float2 rnew = make_float2(rold.x - alpha*Ap.x, rold.y - alpha*Ap.y);
      rbuf[ob] = rnew;
      rnew_s[k] = rnew;
      float pv2 = rnew.x*rnew.x + rnew.y*rnew.y;
      for (int off = 32; off; off >>= 1) pv2 += __shfl_down(pv2, off);
      if (j == 0) redv[w] = pv2;   // w in 0..3 here
    }
    __syncthreads();
    if (tid == 0)
      part[ROW_RS(iter)*1024 + s*256 + row] = redv[0]+redv[1]+redv[2]+redv[3];
  } else {
    // MODE 0: stage r0 row
    if (tid < 256){
      size_t ob = (size_t)s*HW + row*256 + tid;
      rnew_s[tid] = rbuf[ob];
    }
    __syncthreads();
  }

  // --- phase 3: FFT S_c * r_new -> bufR row-major (coalesced)
  {
    int c = w;
    const float2* Sc = sens + (size_t)c*HW + row*256;
    float2 x0 = cmul(Sc[j],     rnew_s[j]);
    float2 x1 = cmul(Sc[j+64],  rnew_s[j+64]);
    float2 x2 = cmul(Sc[j+128], rnew_s[j+128]);
    float2 x3 = cmul(Sc[j+192], rnew_s[j+192]);
    fft256<1>(scratch[c], j, wA,wB,wC, x0,x1,x2,x3);
    float2* d = bufR + ((size_t)(c*3+s))*HW + row*256;
    d[j]=x0; d[j+64]=x1; d[j+128]=x2; d[j+192]=x3;
  }
}

// ---------- COL kernel: 8 columns per block, 768 thr = 12 waves (2 cols each).
// gather bufR (64B/line chunks) -> col FFT(+1) -> U = W*V (+ rMr Parseval Re) ->
// col IFFT(-1) -> scatter bufB row-major. Stateless in p (no Kp buffer).
__global__ __launch_bounds__(768) void k_colW(const float2* __restrict__ bufR,
                                              float2* __restrict__ bufB,
                                              const float* __restrict__ W9,
                                              float* __restrict__ part, int iter){
  __shared__ float2 T[24][256];   // 48 KB: [s*8 + local_col][row]
  __shared__ float redp[12];
  int tid = threadIdx.x, w = tid >> 6, j = tid & 63;
  float2 wA = twf((j&3)<<4), wB = twf((j&15)<<2), wC = twf(j);
  int kg = blockIdx.x, c = blockIdx.y;
  int s = w >> 2, kxp = w & 3;
  int kxl0 = kxp*2, kxl1 = kxl0 + 1;
  int kx0 = kg*8 + kxl0, kx1 = kg*8 + kxl1;

  // --- gather: 3 planes x 8 cols x 256 rows = 3072 float4, 4 per thread
  #pragma unroll
  for (int f = 0; f < 4; f++){
    int idx = f*768 + tid;
    int sp = idx >> 10, rem = idx & 1023, rrow = rem >> 2, cp = rem & 3;
    const float4* s4 = (const float4*)(bufR + ((size_t)(c*3+sp))*HW);
    float4 v = s4[(size_t)rrow*128 + kg*4 + cp];
    T[sp*8 + cp*2 + 0][rrow] = make_float2(v.x, v.y);
    T[sp*8 + cp*2 + 1][rrow] = make_float2(v.z, v.w);
  }
  __syncthreads();

  // --- col FFT(+1), 2 columns per wave, in place
  {
    float2 a0=T[s*8+kxl0][j], a1=T[s*8+kxl0][j+64], a2=T[s*8+kxl0][j+128], a3=T[s*8+kxl0][j+192];
    float2 b0=T[s*8+kxl1][j], b1=T[s*8+kxl1][j+64], b2=T[s*8+kxl1][j+128], b3=T[s*8+kxl1][j+192];
    fft256x2<1>(T[s*8+kxl0], T[s*8+kxl1], j, wA,wB,wC, a0,a1,a2,a3, b0,b1,b2,b3);
    T[s*8+kxl0][j]=a0; T[s*8+kxl0][j+64]=a1; T[s*8+kxl0][j+128]=a2; T[s*8+kxl0][j+192]=a3;
    T[s*8+kxl1][j]=b0; T[s*8+kxl1][j+64]=b1; T[s*8+kxl1][j+128]=b2; T[s*8+kxl1][j+192]=b3;
  }
  __syncthreads();

  // --- U = W V + Parseval rMr partial (Re only; exact-math Im sums to 0)
  float2 UA[4], UB[4];
  float pr = 0.f;
  #pragma unroll
  for (int q = 0; q < 4; q++){
    int k = j + 64*q;
    {
      float2 v0 = T[0+kxl0][k], v1 = T[8+kxl0][k], v2 = T[16+kxl0][k];
      float2 U = w_combine(W9, kx0*256 + k, s, v0, v1, v2);
      UA[q] = U;
      float2 vs = (s==0) ? v0 : ((s==1) ? v1 : v2);
      pr += vs.x*U.x + vs.y*U.y;
    }
    {
      float2 v0 = T[0+kxl1][k], v1 = T[8+kxl1][k], v2 = T[16+kxl1][k];
      float2 U = w_combine(W9, kx1*256 + k, s, v0, v1, v2);
      UB[q] = U;
      float2 vs = (s==0) ? v0 : ((s==1) ? v1 : v2);
      pr += vs.x*U.x + vs.y*U.y;
    }
  }
  __syncthreads();   // all V reads done before T reused as IFFT scratch

  // --- col IFFT(-1)
  {
    float2 a0=UA[0], a1=UA[1], a2=UA[2], a3=UA[3];
    float2 b0=UB[0], b1=UB[1], b2=UB[2], b3=UB[3];
    fft256x2<-1>(T[s*8+kxl0], T[s*8+kxl1], j, wA,wB,wC, a0,a1,a2,a3, b0,b1,b2,b3);
    T[s*8+kxl0][j]=a0; T[s*8+kxl0][j+64]=a1; T[s*8+kxl0][j+128]=a2; T[s*8+kxl0][j+192]=a3;
    T[s*8+kxl1][j]=b0; T[s*8+kxl1][j+64]=b1; T[s*8+kxl1][j+128]=b2; T[s*8+kxl1][j+192]=b3;
  }
  // --- reduce rMr partial
  for (int off = 32; off; off >>= 1) pr += __shfl_down(pr, off);
  if (j == 0) redp[w] = pr;
  __syncthreads();
  if (tid == 0){
    float t = 0.f;
    #pragma unroll
    for (int k = 0; k < 12; k++) t += redp[k];
    part[ROW_RMR(iter)*1024 + c*32 + kg] = t;
  }
  // --- scatter to bufB row-major (mirror of gather)
  #pragma unroll
  for (int f = 0; f < 4; f++){
    int idx = f*768 + tid;
    int sp = idx >> 10, rem = idx & 1023, rrow = rem >> 2, cp = rem & 3;
    float2 a = T[sp*8 + cp*2 + 0][rrow], b = T[sp*8 + cp*2 + 1][rrow];
    float4* d4 = (float4*)(bufB + ((size_t)(c*3+sp))*HW);
    d4[(size_t)rrow*128 + kg*4 + cp] = make_float4(a.x,a.y,b.x,b.y);
  }
}

// ---------- final: reduce rs_9, rMr_9 ; p9 = r9 + beta9*p8 ; z += alpha9*p9
__global__ __launch_bounds__(256) void k_final(float2* __restrict__ z,
                                               const float2* __restrict__ rbuf,
                                               const float2* __restrict__ pbuf,
                                               const float* __restrict__ scal,
                                               const float* __restrict__ part){
  __shared__ float redv[4];
  __shared__ float sA[2];
  int tid = threadIdx.x, w = tid >> 6, j = tid & 63;
  int rowsel[2] = { ROW_RS(9), ROW_RMR(9) };
  #pragma unroll
  for (int q = 0; q < 2; q++){
    const float* P = part + rowsel[q]*1024;
    float v = P[tid] + P[tid+256] + P[tid+512] + P[tid+768];
    for (int off = 32; off; off >>= 1) v += __shfl_down(v, off);
    if (j == 0) redv[w] = v;
    __syncthreads();
    if (tid == 0) sA[q] = redv[0]+redv[1]+redv[2]+redv[3];
    __syncthreads();
  }
  float alpha, beta;
  cg_chain3(scal, 10, sA[0], sA[1], alpha, beta);
  int idx = blockIdx.x*256 + tid;
  float2 r9 = rbuf[idx], p8 = pbuf[idx];
  float2 p9 = cadd(r9, cscale(p8, beta));
  float2 zo = z[idx];
  z[idx] = make_float2(zo.x + alpha*p9.x, zo.y + alpha*p9.y);
}

extern "C" void kernel_launch(void* const* d_in, const int* in_sizes, int n_in,
                              void* d_out, int out_size, void* d_ws, size_t ws_size,
                              hipStream_t stream){
  const float2* y    = (const float2*)d_in[0];
  const float2* mo   = (const float2*)d_in[1];
  const float2* sens = (const float2*)d_in[2];
  const float2* Lt   = (const float2*)d_in[3];
  const float*  mask = (const float*)d_in[4];

  float* w = (float*)d_ws;
  float*  scal = w;                                   // 128 floats (rs chain + rMr chain)
  float*  part = w + 128;                             // 26*1024 floats
  float*  W9   = part + NPART_ROWS*1024;              // 9*HW floats
  float2* bufB = (float2*)(W9 + 9*HW);                // 30 planes row-major
  float2* bufR = bufB + (size_t)30*HW;                // 30 planes row-major k-rows
  float2* rb   = bufR + (size_t)30*HW;                // 3 planes residual
  float2* pb   = rb + (size_t)3*HW;                   // 3 planes direction
  float2* Mpb  = pb + (size_t)3*HW;                   // 3 planes M*p recurrence
  float2* z    = (float2*)d_out;

  // setup: b-vector via adjoint path (verified r4-r9 kernels)
  k_setup<<<2816, 256, 0, stream>>>(mask, Lt, y, W9, bufB, scal, part);
  k_rows_plain<<<dim3(32, 30), 512, 0, stream>>>(bufB, bufR);
  k_cols_plain<<<dim3(32, 30), 512, 0, stream>>>(bufR, bufB);
  k_compute_b<<<768, 256, 0, stream>>>(bufB, sens, mo, rb, z, part);

  // r0 -> k-space rows
  k_bigrow<0><<<dim3(256, 3), 640, 0, stream>>>(bufB, sens, rb, pb, Mpb, z, bufR, scal, part, 0);

  // CG loop: 2 kernels per iteration
  for (int it = 0; it < 10; it++){
    if (it > 0)
      k_bigrow<1><<<dim3(256, 3), 640, 0, stream>>>(bufB, sens, rb, pb, Mpb, z, bufR, scal, part, it);
    k_colW<<<dim3(32, 10), 768, 0, stream>>>(bufR, bufB, W9, part, it);
  }
  k_final<<<768, 256, 0, stream>>>(z, rb, pb, scal, part);
}

// Round 11
// 528.447 us; speedup vs baseline: 1.2205x; 1.0020x over previous
//
#include <hip/hip_runtime.h>
#include <math.h>

#define HW 65536
#define NC 10
#define NT 12
#define LAMBDA_F 0.05f
#define PI_F 3.14159265358979323846f
// XOR-swizzle for wave-private LDS fft scratch
#define SWZ(i) ((i) ^ ((i) >> 4))
// part buffer rows (1024 floats each)
#define ROW_RS(it)  (it)            // rs_it partials: rows 0..9 (768 entries)
#define ROW_RMR(it) (16 + (it))     // rMr_it partials: rows 16..25 (320 entries)
#define NPART_ROWS 26

__device__ __forceinline__ float2 cadd(float2 a, float2 b){ return make_float2(a.x+b.x, a.y+b.y); }
__device__ __forceinline__ float2 csub(float2 a, float2 b){ return make_float2(a.x-b.x, a.y-b.y); }
__device__ __forceinline__ float2 cmul(float2 a, float2 b){ return make_float2(a.x*b.x-a.y*b.y, a.x*b.y+a.y*b.x); }
// conj(a)*b
__device__ __forceinline__ float2 cmulj(float2 a, float2 b){ return make_float2(a.x*b.x+a.y*b.y, a.x*b.y-a.y*b.x); }
__device__ __forceinline__ float2 cscale(float2 a, float s){ return make_float2(a.x*s, a.y*s); }

template<int SIGN>
__device__ __forceinline__ void radix4_nt(float2& a0, float2& a1, float2& a2, float2& a3){
  float2 t0=cadd(a0,a2), t1=csub(a0,a2), t2=cadd(a1,a3), t3=csub(a1,a3);
  float2 t3r;
  if constexpr (SIGN < 0) t3r = make_float2(t3.y, -t3.x); else t3r = make_float2(-t3.y, t3.x);
  a0=cadd(t0,t2); a1=cadd(t1,t3r); a2=csub(t0,t2); a3=csub(t1,t3r);
}

template<int SIGN>
__device__ __forceinline__ void radix4_tw(float2& a0, float2& a1, float2& a2, float2& a3, float2 w){
  if constexpr (SIGN > 0) w.y = -w.y;
  float2 w2 = cmul(w, w);
  float2 w3 = cmul(w, w2);
  a1 = cmul(a1, w); a2 = cmul(a2, w2); a3 = cmul(a3, w3);
  radix4_nt<SIGN>(a0, a1, a2, a3);
}

__device__ __forceinline__ float2 twf(int e){
  float s, c;
  __sincosf(-2.0f*PI_F*(float)e*(1.0f/256.0f), &s, &c);
  return make_float2(c, s);
}

// Single 256-pt Stockham radix-4 FFT, wave-private scratch b.
template<int SIGN>
__device__ __forceinline__ void fft256(float2* b, int j,
                                       float2 wA, float2 wB, float2 wC,
                                       float2& x0, float2& x1, float2& x2, float2& x3){
  radix4_nt<SIGN>(x0,x1,x2,x3);
  b[SWZ(4*j)]=x0; b[SWZ(4*j+1)]=x1; b[SWZ(4*j+2)]=x2; b[SWZ(4*j+3)]=x3;
  x0=b[SWZ(j)]; x1=b[SWZ(j+64)]; x2=b[SWZ(j+128)]; x3=b[SWZ(j+192)];
  radix4_tw<SIGN>(x0,x1,x2,x3, wA);
  { int i=((j>>2)<<4)+(j&3); b[SWZ(i)]=x0; b[SWZ(i+4)]=x1; b[SWZ(i+8)]=x2; b[SWZ(i+12)]=x3; }
  x0=b[SWZ(j)]; x1=b[SWZ(j+64)]; x2=b[SWZ(j+128)]; x3=b[SWZ(j+192)];
  radix4_tw<SIGN>(x0,x1,x2,x3, wB);
  { int i=((j>>4)<<6)+(j&15); b[SWZ(i)]=x0; b[SWZ(i+16)]=x1; b[SWZ(i+32)]=x2; b[SWZ(i+48)]=x3; }
  x0=b[SWZ(j)]; x1=b[SWZ(j+64)]; x2=b[SWZ(j+128)]; x3=b[SWZ(j+192)];
  radix4_tw<SIGN>(x0,x1,x2,x3, wC);
}

// Two independent FFTs, stage-interleaved (r8-r10, verified).
template<int SIGN>
__device__ __forceinline__ void fft256x2(float2* bA, float2* bB, int j,
    float2 wA, float2 wB, float2 wC,
    float2& a0, float2& a1, float2& a2, float2& a3,
    float2& b0, float2& b1, float2& b2, float2& b3){
  radix4_nt<SIGN>(a0,a1,a2,a3); radix4_nt<SIGN>(b0,b1,b2,b3);
  bA[SWZ(4*j)]=a0; bA[SWZ(4*j+1)]=a1; bA[SWZ(4*j+2)]=a2; bA[SWZ(4*j+3)]=a3;
  bB[SWZ(4*j)]=b0; bB[SWZ(4*j+1)]=b1; bB[SWZ(4*j+2)]=b2; bB[SWZ(4*j+3)]=b3;
  a0=bA[SWZ(j)]; a1=bA[SWZ(j+64)]; a2=bA[SWZ(j+128)]; a3=bA[SWZ(j+192)];
  b0=bB[SWZ(j)]; b1=bB[SWZ(j+64)]; b2=bB[SWZ(j+128)]; b3=bB[SWZ(j+192)];
  radix4_tw<SIGN>(a0,a1,a2,a3, wA); radix4_tw<SIGN>(b0,b1,b2,b3, wA);
  { int i=((j>>2)<<4)+(j&3);
    bA[SWZ(i)]=a0; bA[SWZ(i+4)]=a1; bA[SWZ(i+8)]=a2; bA[SWZ(i+12)]=a3;
    bB[SWZ(i)]=b0; bB[SWZ(i+4)]=b1; bB[SWZ(i+8)]=b2; bB[SWZ(i+12)]=b3; }
  a0=bA[SWZ(j)]; a1=bA[SWZ(j+64)]; a2=bA[SWZ(j+128)]; a3=bA[SWZ(j+192)];
  b0=bB[SWZ(j)]; b1=bB[SWZ(j+64)]; b2=bB[SWZ(j+128)]; b3=bB[SWZ(j+192)];
  radix4_tw<SIGN>(a0,a1,a2,a3, wB); radix4_tw<SIGN>(b0,b1,b2,b3, wB);
  { int i=((j>>4)<<6)+(j&15);
    bA[SWZ(i)]=a0; bA[SWZ(i+16)]=a1; bA[SWZ(i+32)]=a2; bA[SWZ(i+48)]=a3;
    bB[SWZ(i)]=b0; bB[SWZ(i+16)]=b1; bB[SWZ(i+32)]=b2; bB[SWZ(i+48)]=b3; }
  a0=bA[SWZ(j)]; a1=bA[SWZ(j+64)]; a2=bA[SWZ(j+128)]; a3=bA[SWZ(j+192)];
  b0=bB[SWZ(j)]; b1=bB[SWZ(j+64)]; b2=bB[SWZ(j+128)]; b3=bB[SWZ(j+192)];
  radix4_tw<SIGN>(a0,a1,a2,a3, wC); radix4_tw<SIGN>(b0,b1,b2,b3, wC);
}

// Exact-CG scalar chain (Hermitian M -> all scalars real). Verified r10.
__device__ __forceinline__ void cg_chain3(const float* __restrict__ scal, int n,
                                          float rs_f, float rmr_f,
                                          float& alpha, float& beta){
  float mp = 0.f, P2 = 0.f, rs_prev = 1.f;
  alpha = 0.f; beta = 0.f;
  for (int k = 0; k < n; k++){
    float rsk  = (k == n-1) ? rs_f  : scal[k];
    float rmrk = (k == n-1) ? rmr_f : scal[32+k];
    if (k == 0){ beta = 0.f; mp = rmrk; P2 = rsk; }
    else {
      beta = rsk / rs_prev;
      mp = rmrk - 2.f*beta*rsk/alpha + beta*beta*mp;
      P2 = rsk + beta*beta*P2;
    }
    float pap = mp + LAMBDA_F*P2;
    alpha = rsk / pap;
    rs_prev = rsk;
  }
}

// W-combine for one output plane s (wave-uniform s -> no divergence)
__device__ __forceinline__ float2 w_combine(const float* __restrict__ W9, int wi, int s,
                                            float2 v0, float2 v1, float2 v2){
  if (s == 0){
    float d0 = W9[wi];
    float2 o01 = make_float2(W9[wi+3*HW], W9[wi+4*HW]);
    float2 o02 = make_float2(W9[wi+5*HW], W9[wi+6*HW]);
    return cadd(cadd(cscale(v0,d0), cmul(o01,v1)), cmul(o02,v2));
  } else if (s == 1){
    float d1 = W9[wi+HW];
    float2 o01 = make_float2(W9[wi+3*HW], W9[wi+4*HW]);
    float2 o12 = make_float2(W9[wi+7*HW], W9[wi+8*HW]);
    return cadd(cadd(cmulj(o01,v0), cscale(v1,d1)), cmul(o12,v2));
  } else {
    float d2 = W9[wi+2*HW];
    float2 o02 = make_float2(W9[wi+5*HW], W9[wi+6*HW]);
    float2 o12 = make_float2(W9[wi+7*HW], W9[wi+8*HW]);
    return cadd(cadd(cmulj(o02,v0), cmulj(o12,v1)), cscale(v2,d2));
  }
}

// ---------- W9 precompute + zero scal/part (small, 256 blocks)
__global__ __launch_bounds__(256) void k_W9(const float* __restrict__ mask,
                                            const float2* __restrict__ Lt,
                                            float* __restrict__ W9,
                                            float* __restrict__ scal,
                                            float* __restrict__ part){
  int tid = threadIdx.x, u = blockIdx.x;
  if (u == 0){
    if (tid < 128) scal[tid] = 0.0f;
    for (int i = tid; i < NPART_ROWS*1024; i += 256) part[i] = 0.0f;
  }
  int kx = u, ky = tid;
  int mx = (kx + 128) & 255, my = (ky + 128) & 255;
  float d0=0.f,d1=0.f,d2=0.f;
  float2 o01=make_float2(0,0), o02=make_float2(0,0), o12=make_float2(0,0);
  for (int t = 0; t < NT; t++){
    float m = mask[t*HW + my*256 + mx];
    float2 l0 = Lt[t*3+0], l1 = Lt[t*3+1], l2 = Lt[t*3+2];
    d0 += m*(l0.x*l0.x + l0.y*l0.y);
    d1 += m*(l1.x*l1.x + l1.y*l1.y);
    d2 += m*(l2.x*l2.x + l2.y*l2.y);
    o01 = cadd(o01, cscale(cmulj(l0,l1), m));
    o02 = cadd(o02, cscale(cmulj(l0,l2), m));
    o12 = cadd(o12, cscale(cmulj(l1,l2), m));
  }
  const float nrm = 1.0f/65536.0f;
  int idx = kx*256 + ky;
  W9[idx]      = d0*nrm;  W9[idx+HW]   = d1*nrm;  W9[idx+2*HW] = d2*nrm;
  W9[idx+3*HW] = o01.x*nrm; W9[idx+4*HW] = o01.y*nrm;
  W9[idx+5*HW] = o02.x*nrm; W9[idx+6*HW] = o02.y*nrm;
  W9[idx+7*HW] = o12.x*nrm; W9[idx+8*HW] = o12.y*nrm;
}

// ---------- FUSED setup row pass: g_{c,s} = D sum_t conj(L_ts) y[t,c] computed
// in registers (3 s-planes share the y row reads), row-IFFT (-1), transposed
// write -> bufR [pl][kx][y]. grid (32 row-tiles, 10 c), 512 thr = 8 waves x 1 row.
__global__ __launch_bounds__(512) void k_rows_g(const float2* __restrict__ y,
                                                const float2* __restrict__ Lt,
                                                float2* __restrict__ dst){
  __shared__ float2 T[8][3][256];   // 48 KB: [local_row][s][elem] (elem = wave scratch)
  int tid = threadIdx.x, g = tid >> 6, j = tid & 63;
  float2 wA = twf((j&3)<<4), wB = twf((j&15)<<2), wC = twf(j);
  int ri = blockIdx.x, c = blockIdx.y;
  int row = ri*8 + g;
  // accumulate g for 3 s, 4 elements each
  float2 acc[3][4];
  #pragma unroll
  for (int s = 0; s < 3; s++)
    #pragma unroll
    for (int q = 0; q < 4; q++) acc[s][q] = make_float2(0,0);
  for (int t = 0; t < NT; t++){
    const float2* yr = y + ((size_t)(t*NC + c))*HW + row*256;
    float2 l0 = Lt[t*3+0], l1 = Lt[t*3+1], l2 = Lt[t*3+2];
    #pragma unroll
    for (int q = 0; q < 4; q++){
      float2 yv = yr[j + 64*q];
      acc[0][q] = cadd(acc[0][q], cmulj(l0, yv));
      acc[1][q] = cadd(acc[1][q], cmulj(l1, yv));
      acc[2][q] = cadd(acc[2][q], cmulj(l2, yv));
    }
  }
  // D sign + row IFFT per s
  #pragma unroll
  for (int s = 0; s < 3; s++){
    float2 x0, x1, x2, x3;
    {
      float sg0 = ((j     + row) & 1) ? -1.0f : 1.0f;
      x0 = cscale(acc[s][0], sg0);
      x1 = cscale(acc[s][1], sg0);      // col j+64: same parity as j
      x2 = cscale(acc[s][2], sg0);
      x3 = cscale(acc[s][3], sg0);
    }
    fft256<-1>(T[g][s], j, wA,wB,wC, x0,x1,x2,x3);
    T[g][s][j]=x0; T[g][s][j+64]=x1; T[g][s][j+128]=x2; T[g][s][j+192]=x3;
  }
  __syncthreads();
  // transposed scatter: 3 planes
  int yo2 = (tid&3)*2, kxo = tid>>2;
  #pragma unroll
  for (int s = 0; s < 3; s++){
    float2* dT = dst + ((size_t)(c*3+s))*HW;
    #pragma unroll
    for (int kb = 0; kb < 2; kb++){
      int kx = kb*128 + kxo;
      float2 a = T[yo2][s][kx], b = T[yo2+1][s][kx];
      *(float4*)(dT + (size_t)kx*256 + ri*8 + yo2) = make_float4(a.x,a.y,b.x,b.y);
    }
  }
}

// ---------- setup col IFFT (-1): bufR [pl][kx][y] contiguous -> bufB row-major
__global__ __launch_bounds__(512) void k_cols_plain(const float2* __restrict__ src,
                                                    float2* __restrict__ dst){
  __shared__ float2 tile[8][256];
  int tid = threadIdx.x, g = tid >> 6, j = tid & 63;
  float2 wA = twf((j&3)<<4), wB = twf((j&15)<<2), wC = twf(j);
  int pl = blockIdx.y, kg = blockIdx.x;
  int kx = kg*8 + g;
  const float2* col = src + (size_t)pl*HW + (size_t)kx*256;
  float2 x0=col[j], x1=col[j+64], x2=col[j+128], x3=col[j+192];
  fft256<-1>(tile[g], j, wA,wB,wC, x0,x1,x2,x3);
  tile[g][j]=x0; tile[g][j+64]=x1; tile[g][j+128]=x2; tile[g][j+192]=x3;
  __syncthreads();
  float2* d = dst + (size_t)pl*HW;
  int kxo2 = (tid&3)*2, yy = tid>>2;
  #pragma unroll
  for (int yb = 0; yb < 2; yb++){
    int yc = yb*128 + yy;
    float2 a = tile[kxo2][yc], b = tile[kxo2+1][yc];
    *(float4*)(d + (size_t)yc*256 + kg*8 + kxo2) = make_float4(a.x,a.y,b.x,b.y);
  }
}

// ---------- BIG-ROW kernel. grid (256 rows, 3 s), 640 thr = 10 waves (wave = coil).
// MODE 0: b = D*sum_c conj(S_c)*A + lambda*mo ; r0=b ; z=0 ; rs0 partial ;
//         then FFT S_c*r0 -> bufR (fused old compute_b + bigrow<0>).
// MODE 1 (iter>=1): bufB holds K2(S r_{it-1}) -> row-IFFT + combine = Mr_{it-1};
//   chain -> alpha,beta; p/Mp/z/r updates; rs_it partial; FFT S_c*r_new -> bufR.
template<int MODE>
__global__ __launch_bounds__(640) void k_bigrow(const float2* __restrict__ bufB,
                                                const float2* __restrict__ sens,
                                                const float2* __restrict__ mo,
                                                float2* __restrict__ rbuf,
                                                float2* __restrict__ pbuf,
                                                float2* __restrict__ Mpb,
                                                float2* __restrict__ zbuf,
                                                float2* __restrict__ bufR,
                                                float* __restrict__ scal,
                                                float* __restrict__ part, int iter){
  __shared__ float2 scratch[10][256];
  __shared__ float2 rnew_s[256];
  __shared__ float redv[10];
  __shared__ float sA[2];
  int tid = threadIdx.x, w = tid >> 6, j = tid & 63;
  float2 wA = twf((j&3)<<4), wB = twf((j&15)<<2), wC = twf(j);
  int row = blockIdx.x, s = blockIdx.y;

  if constexpr (MODE == 1){
    // --- reduce fresh scalar partials: rs_{it-1} (768) and rMr_{it-1} (320)
    int rowsel[2] = { ROW_RS(iter-1), ROW_RMR(iter-1) };
    #pragma unroll
    for (int q = 0; q < 2; q++){
      const float* P = part + rowsel[q]*1024;
      float v = P[tid] + ((tid < 384) ? P[tid+640] : 0.f);
      for (int off = 32; off; off >>= 1) v += __shfl_down(v, off);
      if (j == 0) redv[w] = v;
      __syncthreads();
      if (tid == 0){
        float t = 0.f;
        #pragma unroll
        for (int k = 0; k < 10; k++) t += redv[k];
        sA[q] = t;
      }
      __syncthreads();
    }
    float alpha, beta;
    cg_chain3(scal, iter, sA[0], sA[1], alpha, beta);
    if (blockIdx.x == 0 && blockIdx.y == 0 && tid == 0){
      scal[iter-1]    = sA[0];
      scal[32+iter-1] = sA[1];
    }

    // --- phase 1: row IFFT of bufB per coil + conj(S)
    {
      int c = w;
      const float2* src = bufB + ((size_t)(c*3+s))*HW + row*256;
      float2 x0=src[j], x1=src[j+64], x2=src[j+128], x3=src[j+192];
      fft256<-1>(scratch[c], j, wA,wB,wC, x0,x1,x2,x3);
      const float2* Sc = sens + (size_t)c*HW + row*256;
      scratch[c][j]     = cmulj(Sc[j],     x0);
      scratch[c][j+64]  = cmulj(Sc[j+64],  x1);
      scratch[c][j+128] = cmulj(Sc[j+128], x2);
      scratch[c][j+192] = cmulj(Sc[j+192], x3);
    }
    __syncthreads();
    // --- phase 2: combine -> Mr; CG updates (threads 0..255)
    if (tid < 256){
      int k = tid;
      float2 Mr = make_float2(0,0);
      #pragma unroll
      for (int c = 0; c < NC; c++) Mr = cadd(Mr, scratch[c][k]);
      size_t ob = (size_t)s*HW + row*256 + k;
      float2 rold = rbuf[ob];
      float2 pcur, Mpc;
      if (iter == 1){ pcur = rold; Mpc = Mr; }
      else {
        pcur = cadd(rold, cscale(pbuf[ob], beta));
        Mpc  = cadd(Mr,   cscale(Mpb[ob],  beta));
      }
      Mpb[ob]  = Mpc;
      pbuf[ob] = pcur;
      float2 Ap = cadd(Mpc, cscale(pcur, LAMBDA_F));
      float2 zo = zbuf[ob];
      zbuf[ob] = make_float2(zo.x + alpha*pcur.x, zo.y + alpha*pcur.y);
      float2 rnew = make_float2(rold.x - alpha*Ap.x, rold.y - alpha*Ap.y);
      rbuf[ob] = rnew;
      rnew_s[k] = rnew;
      float pv2 = rnew.x*rnew.x + rnew.y*rnew.y;
      for (int off = 32; off; off >>= 1) pv2 += __shfl_down(pv2, off);
      if (j == 0) redv[w] = pv2;   // w in 0..3 here
    }
    __syncthreads();
    if (tid == 0)
      part[ROW_RS(iter)*1024 + s*256 + row] = redv[0]+redv[1]+redv[2]+redv[3];
  } else {
    // MODE 0: fused compute_b. bufB = A (image planes).
    if (tid < 256){
      int k = tid;
      float sg = ((k + row) & 1) ? -1.0f : 1.0f;
      float2 accv = make_float2(0,0);
      #pragma unroll
      for (int c = 0; c < NC; c++)
        accv = cadd(accv, cmulj(sens[(size_t)c*HW + row*256 + k],
                                bufB[((size_t)(c*3+s))*HW + row*256 + k]));
      size_t ob = (size_t)s*HW + row*256 + k;
      float2 b = cadd(cscale(accv, sg), cscale(mo[ob], LAMBDA_F));
      rbuf[ob] = b; zbuf[ob] = make_float2(0,0);
      rnew_s[k] = b;
      float pv2 = b.x*b.x + b.y*b.y;
      for (int off = 32; off; off >>= 1) pv2 += __shfl_down(pv2, off);
      if (j == 0) redv[w] = pv2;
    }
    __syncthreads();
    if (tid == 0)
      part[ROW_RS(0)*1024 + s*256 + row] = redv[0]+redv[1]+redv[2]+redv[3];
  }

  // --- phase 3: FFT S_c * r_new -> bufR row-major (coalesced)
  {
    int c = w;
    const float2* Sc = sens + (size_t)c*HW + row*256;
    float2 x0 = cmul(Sc[j],     rnew_s[j]);
    float2 x1 = cmul(Sc[j+64],  rnew_s[j+64]);
    float2 x2 = cmul(Sc[j+128], rnew_s[j+128]);
    float2 x3 = cmul(Sc[j+192], rnew_s[j+192]);
    fft256<1>(scratch[c], j, wA,wB,wC, x0,x1,x2,x3);
    float2* d = bufR + ((size_t)(c*3+s))*HW + row*256;
    d[j]=x0; d[j+64]=x1; d[j+128]=x2; d[j+192]=x3;
  }
}

// ---------- COL kernel: 8 columns per block, 768 thr = 12 waves (2 cols each).
// gather bufR (64B/line chunks) -> col FFT(+1) -> U = W*V (+ rMr Parseval Re) ->
// col IFFT(-1) -> scatter bufB row-major. Verified r10.
__global__ __launch_bounds__(768) void k_colW(const float2* __restrict__ bufR,
                                              float2* __restrict__ bufB,
                                              const float* __restrict__ W9,
                                              float* __restrict__ part, int iter){
  __shared__ float2 T[24][256];   // 48 KB: [s*8 + local_col][row]
  __shared__ float redp[12];
  int tid = threadIdx.x, w = tid >> 6, j = tid & 63;
  float2 wA = twf((j&3)<<4), wB = twf((j&15)<<2), wC = twf(j);
  int kg = blockIdx.x, c = blockIdx.y;
  int s = w >> 2, kxp = w & 3;
  int kxl0 = kxp*2, kxl1 = kxl0 + 1;
  int kx0 = kg*8 + kxl0, kx1 = kg*8 + kxl1;

  // --- gather: 3 planes x 8 cols x 256 rows = 3072 float4, 4 per thread
  #pragma unroll
  for (int f = 0; f < 4; f++){
    int idx = f*768 + tid;
    int sp = idx >> 10, rem = idx & 1023, rrow = rem >> 2, cp = rem & 3;
    const float4* s4 = (const float4*)(bufR + ((size_t)(c*3+sp))*HW);
    float4 v = s4[(size_t)rrow*128 + kg*4 + cp];
    T[sp*8 + cp*2 + 0][rrow] = make_float2(v.x, v.y);
    T[sp*8 + cp*2 + 1][rrow] = make_float2(v.z, v.w);
  }
  __syncthreads();

  // --- col FFT(+1), 2 columns per wave, in place
  {
    float2 a0=T[s*8+kxl0][j], a1=T[s*8+kxl0][j+64], a2=T[s*8+kxl0][j+128], a3=T[s*8+kxl0][j+192];
    float2 b0=T[s*8+kxl1][j], b1=T[s*8+kxl1][j+64], b2=T[s*8+kxl1][j+128], b3=T[s*8+kxl1][j+192];
    fft256x2<1>(T[s*8+kxl0], T[s*8+kxl1], j, wA,wB,wC, a0,a1,a2,a3, b0,b1,b2,b3);
    T[s*8+kxl0][j]=a0; T[s*8+kxl0][j+64]=a1; T[s*8+kxl0][j+128]=a2; T[s*8+kxl0][j+192]=a3;
    T[s*8+kxl1][j]=b0; T[s*8+kxl1][j+64]=b1; T[s*8+kxl1][j+128]=b2; T[s*8+kxl1][j+192]=b3;
  }
  __syncthreads();

  // --- U = W V + Parseval rMr partial (Re only; exact-math Im sums to 0)
  float2 UA[4], UB[4];
  float pr = 0.f;
  #pragma unroll
  for (int q = 0; q < 4; q++){
    int k = j + 64*q;
    {
      float2 v0 = T[0+kxl0][k], v1 = T[8+kxl0][k], v2 = T[16+kxl0][k];
      float2 U = w_combine(W9, kx0*256 + k, s, v0, v1, v2);
      UA[q] = U;
      float2 vs = (s==0) ? v0 : ((s==1) ? v1 : v2);
      pr += vs.x*U.x + vs.y*U.y;
    }
    {
      float2 v0 = T[0+kxl1][k], v1 = T[8+kxl1][k], v2 = T[16+kxl1][k];
      float2 U = w_combine(W9, kx1*256 + k, s, v0, v1, v2);
      UB[q] = U;
      float2 vs = (s==0) ? v0 : ((s==1) ? v1 : v2);
      pr += vs.x*U.x + vs.y*U.y;
    }
  }
  __syncthreads();   // all V reads done before T reused as IFFT scratch

  // --- col IFFT(-1)
  {
    float2 a0=UA[0], a1=UA[1], a2=UA[2], a3=UA[3];
    float2 b0=UB[0], b1=UB[1], b2=UB[2], b3=UB[3];
    fft256x2<-1>(T[s*8+kxl0], T[s*8+kxl1], j, wA,wB,wC, a0,a1,a2,a3, b0,b1,b2,b3);
    T[s*8+kxl0][j]=a0; T[s*8+kxl0][j+64]=a1; T[s*8+kxl0][j+128]=a2; T[s*8+kxl0][j+192]=a3;
    T[s*8+kxl1][j]=b0; T[s*8+kxl1][j+64]=b1; T[s*8+kxl1][j+128]=b2; T[s*8+kxl1][j+192]=b3;
  }
  // --- reduce rMr partial
  for (int off = 32; off; off >>= 1) pr += __shfl_down(pr, off);
  if (j == 0) redp[w] = pr;
  __syncthreads();
  if (tid == 0){
    float t = 0.f;
    #pragma unroll
    for (int k = 0; k < 12; k++) t += redp[k];
    part[ROW_RMR(iter)*1024 + c*32 + kg] = t;
  }
  // --- scatter to bufB row-major (mirror of gather)
  #pragma unroll
  for (int f = 0; f < 4; f++){
    int idx = f*768 + tid;
    int sp = idx >> 10, rem = idx & 1023, rrow = rem >> 2, cp = rem & 3;
    float2 a = T[sp*8 + cp*2 + 0][rrow], b = T[sp*8 + cp*2 + 1][rrow];
    float4* d4 = (float4*)(bufB + ((size_t)(c*3+sp))*HW);
    d4[(size_t)rrow*128 + kg*4 + cp] = make_float4(a.x,a.y,b.x,b.y);
  }
}

// ---------- final: reduce rs_9, rMr_9 ; p9 = r9 + beta9*p8 ; z += alpha9*p9
__global__ __launch_bounds__(256) void k_final(float2* __restrict__ z,
                                               const float2* __restrict__ rbuf,
                                               const float2* __restrict__ pbuf,
                                               const float* __restrict__ scal,
                                               const float* __restrict__ part){
  __shared__ float redv[4];
  __shared__ float sA[2];
  int tid = threadIdx.x, w = tid >> 6, j = tid & 63;
  int rowsel[2] = { ROW_RS(9), ROW_RMR(9) };
  #pragma unroll
  for (int q = 0; q < 2; q++){
    const float* P = part + rowsel[q]*1024;
    float v = P[tid] + P[tid+256] + P[tid+512] + P[tid+768];
    for (int off = 32; off; off >>= 1) v += __shfl_down(v, off);
    if (j == 0) redv[w] = v;
    __syncthreads();
    if (tid == 0) sA[q] = redv[0]+redv[1]+redv[2]+redv[3];
    __syncthreads();
  }
  float alpha, beta;
  cg_chain3(scal, 10, sA[0], sA[1], alpha, beta);
  int idx = blockIdx.x*256 + tid;
  float2 r9 = rbuf[idx], p8 = pbuf[idx];
  float2 p9 = cadd(r9, cscale(p8, beta));
  float2 zo = z[idx];
  z[idx] = make_float2(zo.x + alpha*p9.x, zo.y + alpha*p9.y);
}

extern "C" void kernel_launch(void* const* d_in, const int* in_sizes, int n_in,
                              void* d_out, int out_size, void* d_ws, size_t ws_size,
                              hipStream_t stream){
  const float2* y    = (const float2*)d_in[0];
  const float2* mo   = (const float2*)d_in[1];
  const float2* sens = (const float2*)d_in[2];
  const float2* Lt   = (const float2*)d_in[3];
  const float*  mask = (const float*)d_in[4];

  float* w = (float*)d_ws;
  float*  scal = w;                                   // 128 floats (rs chain + rMr chain)
  float*  part = w + 128;                             // 26*1024 floats
  float*  W9   = part + NPART_ROWS*1024;              // 9*HW floats
  float2* bufB = (float2*)(W9 + 9*HW);                // 30 planes row-major
  float2* bufR = bufB + (size_t)30*HW;                // 30 planes row-major k-rows / setup transpose
  float2* rb   = bufR + (size_t)30*HW;                // 3 planes residual
  float2* pb   = rb + (size_t)3*HW;                   // 3 planes direction
  float2* Mpb  = pb + (size_t)3*HW;                   // 3 planes M*p recurrence
  float2* z    = (float2*)d_out;

  // setup (fused): W9 ; g+rowIFFT->bufR_T ; colIFFT->bufB(A) ; b+r0+FFT rows
  k_W9<<<256, 256, 0, stream>>>(mask, Lt, W9, scal, part);
  k_rows_g<<<dim3(32, 10), 512, 0, stream>>>(y, Lt, bufR);
  k_cols_plain<<<dim3(32, 30), 512, 0, stream>>>(bufR, bufB);
  k_bigrow<0><<<dim3(256, 3), 640, 0, stream>>>(bufB, sens, mo, rb, pb, Mpb, z, bufR, scal, part, 0);

  // CG loop: 2 kernels per iteration
  for (int it = 0; it < 10; it++){
    if (it > 0)
      k_bigrow<1><<<dim3(256, 3), 640, 0, stream>>>(bufB, sens, mo, rb, pb, Mpb, z, bufR, scal, part, it);
    k_colW<<<dim3(32, 10), 768, 0, stream>>>(bufR, bufB, W9, part, it);
  }
  k_final<<<768, 256, 0, stream>>>(z, rb, pb, scal, part);
}